// Round 1
// baseline (154.963 us; speedup 1.0000x reference)
//
#include <hip/hip_runtime.h>

using f32x4  = __attribute__((ext_vector_type(4))) float;
using bf16x8 = __attribute__((ext_vector_type(8))) short;

__device__ __forceinline__ ushort f2b(float x) {
  union { float f; unsigned u; } v; v.f = x;
  unsigned u = v.u;
  return (ushort)((u + 0x7FFFu + ((u >> 16) & 1u)) >> 16);
}

// ---- transpose-cast weights: out[n][k] = bf16(in[k][n]), K = 512 fixed ----
__global__ __launch_bounds__(256) void kcastT(const float* __restrict__ in,
                                              ushort* __restrict__ out, int Nc) {
  int i = blockIdx.x * 256 + threadIdx.x;   // grid sized exactly: Nc*512/256 blocks
  int n = i >> 9, k = i & 511;
  out[i] = f2b(in[k * Nc + n]);
}

// ---- cast x (f32 -> bf16), 4 elems/thread ----
__global__ __launch_bounds__(256) void kcastx(const float* __restrict__ in,
                                              ushort* __restrict__ out) {
  int t = blockIdx.x * 256 + threadIdx.x;
  float4 v = ((const float4*)in)[t];
  ushort4 o;
  o.x = f2b(v.x); o.y = f2b(v.y); o.z = f2b(v.z); o.w = f2b(v.w);
  ((ushort4*)out)[t] = o;
}

// ---- bf16 GEMM: C[M][Nc] = A[M][512] * BT[Nc][512]^T + bias ----
// 64x64 tile / workgroup, 4 waves, each wave 16 rows x 64 cols.
__global__ __launch_bounds__(256) void kgemm(const ushort* __restrict__ A,
                                             const ushort* __restrict__ BT,
                                             const float* __restrict__ bias,
                                             float* __restrict__ C, int Nc) {
  __shared__ __align__(16) ushort At[64][72];
  __shared__ __align__(16) ushort Bt[64][72];
  int tid = threadIdx.x;
  int w = tid >> 6, l = tid & 63;
  int l15 = l & 15, lq = l >> 4;
  int bm = blockIdx.x, bn = blockIdx.y;
  f32x4 acc[4];
#pragma unroll
  for (int i = 0; i < 4; i++) acc[i] = (f32x4){0.f, 0.f, 0.f, 0.f};
  int sr = tid >> 3, sc = (tid & 7) * 8;
  const ushort* Abase = A + (size_t)(bm * 64) * 512;
  const ushort* Bbase = BT + (size_t)(bn * 64) * 512;
  for (int kt = 0; kt < 512; kt += 64) {
    __syncthreads();
#pragma unroll
    for (int rr = sr; rr < 64; rr += 32) {
      *(uint4*)&At[rr][sc] = *(const uint4*)(Abase + rr * 512 + kt + sc);
      *(uint4*)&Bt[rr][sc] = *(const uint4*)(Bbase + rr * 512 + kt + sc);
    }
    __syncthreads();
#pragma unroll
    for (int kk = 0; kk < 2; kk++) {
      bf16x8 af = *(const bf16x8*)&At[w * 16 + l15][kk * 32 + lq * 8];
#pragma unroll
      for (int ns = 0; ns < 4; ns++) {
        bf16x8 bfr = *(const bf16x8*)&Bt[ns * 16 + l15][kk * 32 + lq * 8];
        acc[ns] = __builtin_amdgcn_mfma_f32_16x16x32_bf16(af, bfr, acc[ns], 0, 0, 0);
      }
    }
  }
  int orow = bm * 64 + w * 16 + lq * 4;
  int oc = bn * 64 + l15;
#pragma unroll
  for (int ns = 0; ns < 4; ns++) {
    int col = oc + ns * 16;
    float bv = bias[col];
#pragma unroll
    for (int r = 0; r < 4; r++)
      C[(size_t)(orow + r) * Nc + col] = acc[ns][r] + bv;
  }
}

// ---- forward pose maps: qkv(f32) -> qx,kx,vx (bf16, [bh][n][64]) ----
__global__ __launch_bounds__(256) void kposef(const float* __restrict__ qkv,
                                              const float* __restrict__ poses,
                                              ushort* __restrict__ qx,
                                              ushort* __restrict__ kx,
                                              ushort* __restrict__ vx) {
  int token = blockIdx.x * 4 + (threadIdx.x >> 6);   // one wave per token
  int l = threadIdx.x & 63;
  int b = token >> 11, n = token & 2047;
  const float* P = poses + (size_t)token * 16;
  float R00 = P[0], R01 = P[1], R02 = P[2],  t0 = P[3];
  float R10 = P[4], R11 = P[5], R12 = P[6],  t1 = P[7];
  float R20 = P[8], R21 = P[9], R22 = P[10], t2 = P[11];
  float ti0 = -(R00 * t0 + R10 * t1 + R20 * t2);
  float ti1 = -(R01 * t0 + R11 * t1 + R21 * t2);
  float ti2 = -(R02 * t0 + R12 * t1 + R22 * t2);
  const float* row = qkv + (size_t)token * 1536;
#pragma unroll
  for (int it = 0; it < 2; it++) {
    int c = l + it * 64;            // 4-vec index 0..127
    int h = c >> 4, cc = c & 15;
    size_t obase = ((size_t)(b * 8 + h) * 2048 + n) * 64 + cc * 4;
    float4 a; ushort4 o;
    // q: qx = [R a3, ti.a3 + a.w]
    a = *(const float4*)(row + c * 4);
    o.x = f2b(R00 * a.x + R01 * a.y + R02 * a.z);
    o.y = f2b(R10 * a.x + R11 * a.y + R12 * a.z);
    o.z = f2b(R20 * a.x + R21 * a.y + R22 * a.z);
    o.w = f2b(ti0 * a.x + ti1 * a.y + ti2 * a.z + a.w);
    *(ushort4*)(qx + obase) = o;
    // k: kx = [R a3 + t a.w, a.w]
    a = *(const float4*)(row + 512 + c * 4);
    o.x = f2b(R00 * a.x + R01 * a.y + R02 * a.z + t0 * a.w);
    o.y = f2b(R10 * a.x + R11 * a.y + R12 * a.z + t1 * a.w);
    o.z = f2b(R20 * a.x + R21 * a.y + R22 * a.z + t2 * a.w);
    o.w = f2b(a.w);
    *(ushort4*)(kx + obase) = o;
    // v: same map as k
    a = *(const float4*)(row + 1024 + c * 4);
    o.x = f2b(R00 * a.x + R01 * a.y + R02 * a.z + t0 * a.w);
    o.y = f2b(R10 * a.x + R11 * a.y + R12 * a.z + t1 * a.w);
    o.z = f2b(R20 * a.x + R21 * a.y + R22 * a.z + t2 * a.w);
    o.w = f2b(a.w);
    *(ushort4*)(vx + obase) = o;
  }
}

// ---- flash attention: one WG = (bh, 64 q-rows); 4 waves x 16 rows ----
__global__ __launch_bounds__(256) void kattn(const ushort* __restrict__ qx,
                                             const ushort* __restrict__ kx,
                                             const ushort* __restrict__ vx,
                                             float* __restrict__ ao) {
  __shared__ __align__(16) ushort Kt[64][72];         // [key][d]
  __shared__ __align__(16) ushort Vt[64][72];         // transposed: [d][key]
  __shared__ __align__(16) ushort Pt[4][16][72];      // per-wave P tile [qrow][key]
  int tid = threadIdx.x;
  int w = tid >> 6, l = tid & 63;
  int l15 = l & 15, lq = l >> 4;
  int blk = blockIdx.x;
  int bh = blk >> 5, qb = blk & 31;
  const size_t base = (size_t)bh * 2048 * 64;
  int qrow = qb * 64 + w * 16 + l15;
  bf16x8 qf[2];
  qf[0] = *(const bf16x8*)(qx + base + (size_t)qrow * 64 + lq * 8);
  qf[1] = *(const bf16x8*)(qx + base + (size_t)qrow * 64 + 32 + lq * 8);
  f32x4 accO[4];
  float m[4], lsum[4];
#pragma unroll
  for (int i = 0; i < 4; i++) {
    accO[i] = (f32x4){0.f, 0.f, 0.f, 0.f};
    m[i] = -INFINITY; lsum[i] = 0.f;
  }
  const float cs = 0.125f * 1.44269504089f;   // scale * log2(e)
  int sr = tid >> 3, sc = (tid & 7) * 8;
  for (int n0 = 0; n0 < 2048; n0 += 64) {
    __syncthreads();
#pragma unroll
    for (int rr = sr; rr < 64; rr += 32) {
      *(uint4*)&Kt[rr][sc] = *(const uint4*)(kx + base + (size_t)(n0 + rr) * 64 + sc);
      uint4 vv = *(const uint4*)(vx + base + (size_t)(n0 + rr) * 64 + sc);
      const ushort* pv = (const ushort*)&vv;
#pragma unroll
      for (int j = 0; j < 8; j++) Vt[sc + j][rr] = pv[j];   // LDS transpose
    }
    __syncthreads();
    // S = qx * kx^T  (16 rows x 64 keys per wave)
    f32x4 s[4];
#pragma unroll
    for (int i = 0; i < 4; i++) s[i] = (f32x4){0.f, 0.f, 0.f, 0.f};
#pragma unroll
    for (int kk = 0; kk < 2; kk++) {
#pragma unroll
      for (int ns = 0; ns < 4; ns++) {
        bf16x8 bfr = *(const bf16x8*)&Kt[ns * 16 + l15][kk * 32 + lq * 8];
        s[ns] = __builtin_amdgcn_mfma_f32_16x16x32_bf16(qf[kk], bfr, s[ns], 0, 0, 0);
      }
    }
    // online softmax update; lane owns rows 4*lq+r, col l15 (+16*ns)
    float resc[4];
#pragma unroll
    for (int r = 0; r < 4; r++) {
      float v = fmaxf(fmaxf(s[0][r], s[1][r]), fmaxf(s[2][r], s[3][r]));
#pragma unroll
      for (int off = 1; off < 16; off <<= 1)
        v = fmaxf(v, __shfl_xor(v, off, 64));
      float mn = fmaxf(m[r], v * cs);
      resc[r] = exp2f(m[r] - mn);
      m[r] = mn;
    }
#pragma unroll
    for (int r = 0; r < 4; r++) {
      float psum = 0.f;
#pragma unroll
      for (int ns = 0; ns < 4; ns++) {
        float p = exp2f(s[ns][r] * cs - m[r]);
        psum += p;
        Pt[w][lq * 4 + r][ns * 16 + l15] = f2b(p);
      }
#pragma unroll
      for (int off = 1; off < 16; off <<= 1)
        psum += __shfl_xor(psum, off, 64);
      lsum[r] = lsum[r] * resc[r] + psum;
#pragma unroll
      for (int ds = 0; ds < 4; ds++) accO[ds][r] *= resc[r];
    }
    // O += P * V   (A-frag from Pt, B-frag from transposed Vt)
#pragma unroll
    for (int kk = 0; kk < 2; kk++) {
      bf16x8 pa = *(const bf16x8*)&Pt[w][l15][kk * 32 + lq * 8];
#pragma unroll
      for (int ds = 0; ds < 4; ds++) {
        bf16x8 bv = *(const bf16x8*)&Vt[ds * 16 + l15][kk * 32 + lq * 8];
        accO[ds] = __builtin_amdgcn_mfma_f32_16x16x32_bf16(pa, bv, accO[ds], 0, 0, 0);
      }
    }
  }
  int orow = qb * 64 + w * 16 + lq * 4;
#pragma unroll
  for (int ds = 0; ds < 4; ds++)
#pragma unroll
    for (int r = 0; r < 4; r++)
      ao[base + (size_t)(orow + r) * 64 + ds * 16 + l15] = accO[ds][r] / lsum[r];
}

// ---- inverse pose map on attention output + head-concat transpose ----
__global__ __launch_bounds__(256) void kposeb(const float* __restrict__ ao,
                                              const float* __restrict__ poses,
                                              ushort* __restrict__ obuf) {
  int token = blockIdx.x * 4 + (threadIdx.x >> 6);
  int l = threadIdx.x & 63;
  int b = token >> 11, n = token & 2047;
  const float* P = poses + (size_t)token * 16;
  float R00 = P[0], R01 = P[1], R02 = P[2],  t0 = P[3];
  float R10 = P[4], R11 = P[5], R12 = P[6],  t1 = P[7];
  float R20 = P[8], R21 = P[9], R22 = P[10], t2 = P[11];
  float ti0 = -(R00 * t0 + R10 * t1 + R20 * t2);
  float ti1 = -(R01 * t0 + R11 * t1 + R21 * t2);
  float ti2 = -(R02 * t0 + R12 * t1 + R22 * t2);
#pragma unroll
  for (int it = 0; it < 2; it++) {
    int c = l + it * 64;
    int h = c >> 4, cc = c & 15;
    float4 a = *(const float4*)(ao + ((size_t)(b * 8 + h) * 2048 + n) * 64 + cc * 4);
    ushort4 o;
    // o' = invP * o = [R^T o3 + ti*o.w, o.w]
    o.x = f2b(R00 * a.x + R10 * a.y + R20 * a.z + ti0 * a.w);
    o.y = f2b(R01 * a.x + R11 * a.y + R21 * a.z + ti1 * a.w);
    o.z = f2b(R02 * a.x + R12 * a.y + R22 * a.z + ti2 * a.w);
    o.w = f2b(a.w);
    *(ushort4*)(obuf + (size_t)token * 512 + c * 4) = o;
  }
}

extern "C" void kernel_launch(void* const* d_in, const int* in_sizes, int n_in,
                              void* d_out, int out_size, void* d_ws, size_t ws_size,
                              hipStream_t stream) {
  const float* x     = (const float*)d_in[0];
  const float* poses = (const float*)d_in[1];
  const float* w_qkv = (const float*)d_in[2];
  const float* b_qkv = (const float*)d_in[3];
  const float* w_out = (const float*)d_in[4];
  const float* b_out = (const float*)d_in[5];
  float* out = (float*)d_out;
  char* ws = (char*)d_ws;
  const size_t MB = 1024 * 1024;
  ushort* xb    = (ushort*)(ws);            // 4 MB
  ushort* wqkvT = (ushort*)(ws + 4 * MB);   // 1.5 MB
  ushort* woutT = (ushort*)(ws + 6 * MB);   // 0.5 MB
  float*  qkvf  = (float*)(ws + 8 * MB);    // 24 MB  [4096][1536]
  float*  ao    = (float*)(ws + 8 * MB);    // reuse qkvf region after pose_fwd (8 MB)
  ushort* obuf  = (ushort*)(ws + 16 * MB);  // reuse (4 MB)
  ushort* qxb   = (ushort*)(ws + 32 * MB);  // 4 MB each
  ushort* kxb   = (ushort*)(ws + 36 * MB);
  ushort* vxb   = (ushort*)(ws + 40 * MB);

  kcastT<<<3072, 256, 0, stream>>>(w_qkv, wqkvT, 1536);
  kcastT<<<1024, 256, 0, stream>>>(w_out, woutT, 512);
  kcastx<<<2048, 256, 0, stream>>>(x, xb);
  dim3 g1(64, 24);
  kgemm<<<g1, 256, 0, stream>>>(xb, wqkvT, b_qkv, qkvf, 1536);
  kposef<<<1024, 256, 0, stream>>>(qkvf, poses, qxb, kxb, vxb);
  kattn<<<512, 256, 0, stream>>>(qxb, kxb, vxb, ao);
  kposeb<<<1024, 256, 0, stream>>>(ao, poses, obuf);
  dim3 g2(64, 8);
  kgemm<<<g2, 256, 0, stream>>>(obuf, woutT, b_out, out, 512);
}

// Round 2
// 96.632 us; speedup vs baseline: 1.6036x; 1.6036x over previous
//
#include <hip/hip_runtime.h>

using f32x4  = __attribute__((ext_vector_type(4))) float;
using f32x16 = __attribute__((ext_vector_type(16))) float;
using bf16x8 = __attribute__((ext_vector_type(8))) short;

__device__ __forceinline__ ushort f2b(float x) {
  union { float f; unsigned u; } v; v.f = x;
  unsigned u = v.u;
  return (ushort)((u + 0x7FFFu + ((u >> 16) & 1u)) >> 16);
}

__device__ __forceinline__ int cvtpk(float lo, float hi) {
  int r;
  asm("v_cvt_pk_bf16_f32 %0, %1, %2" : "=v"(r) : "v"(lo), "v"(hi));
  return r;
}

// ---- transpose-cast weights: out[n][k] = bf16(in[k][n]), K = 512 fixed ----
__global__ __launch_bounds__(256) void kcastT(const float* __restrict__ in,
                                              ushort* __restrict__ out, int Nc) {
  int i = blockIdx.x * 256 + threadIdx.x;
  int n = i >> 9, k = i & 511;
  out[i] = f2b(in[k * Nc + n]);
}

// ---- cast x (f32 -> bf16), 4 elems/thread ----
__global__ __launch_bounds__(256) void kcastx(const float* __restrict__ in,
                                              ushort* __restrict__ out) {
  int t = blockIdx.x * 256 + threadIdx.x;
  float4 v = ((const float4*)in)[t];
  ushort4 o;
  o.x = f2b(v.x); o.y = f2b(v.y); o.z = f2b(v.z); o.w = f2b(v.w);
  ((ushort4*)out)[t] = o;
}

// ---- bf16 GEMM: C[M][Nc] = A[M][512] * BT[Nc][512]^T + bias ----
__global__ __launch_bounds__(256) void kgemm(const ushort* __restrict__ A,
                                             const ushort* __restrict__ BT,
                                             const float* __restrict__ bias,
                                             float* __restrict__ C, int Nc) {
  __shared__ __align__(16) ushort At[64][72];
  __shared__ __align__(16) ushort Bt[64][72];
  int tid = threadIdx.x;
  int w = tid >> 6, l = tid & 63;
  int l15 = l & 15, lq = l >> 4;
  int bm = blockIdx.x, bn = blockIdx.y;
  f32x4 acc[4];
#pragma unroll
  for (int i = 0; i < 4; i++) acc[i] = (f32x4){0.f, 0.f, 0.f, 0.f};
  int sr = tid >> 3, sc = (tid & 7) * 8;
  const ushort* Abase = A + (size_t)(bm * 64) * 512;
  const ushort* Bbase = BT + (size_t)(bn * 64) * 512;
  for (int kt = 0; kt < 512; kt += 64) {
    __syncthreads();
#pragma unroll
    for (int rr = sr; rr < 64; rr += 32) {
      *(uint4*)&At[rr][sc] = *(const uint4*)(Abase + rr * 512 + kt + sc);
      *(uint4*)&Bt[rr][sc] = *(const uint4*)(Bbase + rr * 512 + kt + sc);
    }
    __syncthreads();
#pragma unroll
    for (int kk = 0; kk < 2; kk++) {
      bf16x8 af = *(const bf16x8*)&At[w * 16 + l15][kk * 32 + lq * 8];
#pragma unroll
      for (int ns = 0; ns < 4; ns++) {
        bf16x8 bfr = *(const bf16x8*)&Bt[ns * 16 + l15][kk * 32 + lq * 8];
        acc[ns] = __builtin_amdgcn_mfma_f32_16x16x32_bf16(af, bfr, acc[ns], 0, 0, 0);
      }
    }
  }
  int orow = bm * 64 + w * 16 + lq * 4;
  int oc = bn * 64 + l15;
#pragma unroll
  for (int ns = 0; ns < 4; ns++) {
    int col = oc + ns * 16;
    float bv = bias[col];
#pragma unroll
    for (int r = 0; r < 4; r++)
      C[(size_t)(orow + r) * Nc + col] = acc[ns][r] + bv;
  }
}

// ---- forward pose maps: qkv(f32) -> qx (row-major) + kxF/vxF (MFMA-frag order) ----
// kxF: [bh][tile=n>>5][kkd=d>>4][hK=(d>>3)&1][cK=n&31][j=d&7]
// vxF: [bh][tile][kv=(n>>4)&1][db=d>>5][hV=(n>>3)&1][cV=d&31][j=n&7]
__global__ __launch_bounds__(256) void kposef2(const float* __restrict__ qkv,
                                               const float* __restrict__ poses,
                                               ushort* __restrict__ qx,
                                               ushort* __restrict__ kxF,
                                               ushort* __restrict__ vxF) {
  int token = blockIdx.x * 4 + (threadIdx.x >> 6);
  int l = threadIdx.x & 63;
  int b = token >> 11, n = token & 2047;
  const float* P = poses + (size_t)token * 16;
  float R00 = P[0], R01 = P[1], R02 = P[2],  t0 = P[3];
  float R10 = P[4], R11 = P[5], R12 = P[6],  t1 = P[7];
  float R20 = P[8], R21 = P[9], R22 = P[10], t2 = P[11];
  float ti0 = -(R00 * t0 + R10 * t1 + R20 * t2);
  float ti1 = -(R01 * t0 + R11 * t1 + R21 * t2);
  float ti2 = -(R02 * t0 + R12 * t1 + R22 * t2);
  const float* row = qkv + (size_t)token * 1536;
  int tile = n >> 5;
  int kvsel = (n >> 4) & 1;
  int hV = (n >> 3) & 1;
  int jV = n & 7;
  int cK = n & 31;
#pragma unroll
  for (int it = 0; it < 2; it++) {
    int cvi = l + it * 64;          // 4-vec index 0..127
    int hh = cvi >> 4, cc = cvi & 15;
    int bh = b * 8 + hh;
    float4 a;
    // q: [R a3, ti.a3 + a.w], row-major qx[bh][n][64]
    a = *(const float4*)(row + cvi * 4);
    ushort4 oq;
    oq.x = f2b(R00 * a.x + R01 * a.y + R02 * a.z);
    oq.y = f2b(R10 * a.x + R11 * a.y + R12 * a.z);
    oq.z = f2b(R20 * a.x + R21 * a.y + R22 * a.z);
    oq.w = f2b(ti0 * a.x + ti1 * a.y + ti2 * a.z + a.w);
    *(ushort4*)(qx + ((size_t)bh * 2048 + n) * 64 + cc * 4) = oq;
    // k: [R a3 + t a.w, a.w] -> kxF frag order
    a = *(const float4*)(row + 512 + cvi * 4);
    ushort4 ok;
    ok.x = f2b(R00 * a.x + R01 * a.y + R02 * a.z + t0 * a.w);
    ok.y = f2b(R10 * a.x + R11 * a.y + R12 * a.z + t1 * a.w);
    ok.z = f2b(R20 * a.x + R21 * a.y + R22 * a.z + t2 * a.w);
    ok.w = f2b(a.w);
    int kkd = cc >> 2, hK = (cc >> 1) & 1, jK0 = (cc & 1) * 4;
    size_t kaddr = ((((size_t)bh * 64 + tile) * 4 + kkd) * 2 + hK) * 256 + cK * 8 + jK0;
    *(ushort4*)(kxF + kaddr) = ok;
    // v: same map as k -> vxF frag order (V^T fragments)
    a = *(const float4*)(row + 1024 + cvi * 4);
    ushort v0 = f2b(R00 * a.x + R01 * a.y + R02 * a.z + t0 * a.w);
    ushort v1 = f2b(R10 * a.x + R11 * a.y + R12 * a.z + t1 * a.w);
    ushort v2 = f2b(R20 * a.x + R21 * a.y + R22 * a.z + t2 * a.w);
    ushort v3 = f2b(a.w);
    int db = cc >> 3;
    int cV0 = (cc * 4) & 31;
    size_t vaddr = (((((size_t)bh * 64 + tile) * 2 + kvsel) * 2 + db) * 2 + hV) * 256
                 + (size_t)cV0 * 8 + jV;
    vxF[vaddr]      = v0;
    vxF[vaddr + 8]  = v1;
    vxF[vaddr + 16] = v2;
    vxF[vaddr + 24] = v3;
  }
}

// ---- attention: WG = (bh, 32 q); 4 waves key-split (512 keys each), no LDS in loop ----
__global__ __launch_bounds__(256) void kattn2(const ushort* __restrict__ qx,
                                              const ushort* __restrict__ kxF,
                                              const ushort* __restrict__ vxF,
                                              const float* __restrict__ poses,
                                              ushort* __restrict__ obuf) {
  __shared__ float Wacc[4][32][68];
  __shared__ float Wm[4][32];
  __shared__ float Wl[4][32];
  const int tid = threadIdx.x;
  const int w = tid >> 6;
  const int l = tid & 63;
  const int c = l & 31;
  const int h = l >> 5;
  const int bid = blockIdx.x;
  const int bh = bid >> 6, qb = bid & 63;

  // Q B-fragments: col = q = c, k(d) = 16*kk + 8*h + j
  const ushort* qp = qx + ((size_t)bh * 2048 + qb * 32 + c) * 64 + h * 8;
  bf16x8 qf0 = *(const bf16x8*)(qp);
  bf16x8 qf1 = *(const bf16x8*)(qp + 16);
  bf16x8 qf2 = *(const bf16x8*)(qp + 32);
  bf16x8 qf3 = *(const bf16x8*)(qp + 48);

  f32x16 accO0, accO1;
#pragma unroll
  for (int j = 0; j < 16; j++) { accO0[j] = 0.f; accO1[j] = 0.f; }
  float m = -INFINITY, lsum = 0.f;
  const float cs = 0.125f * 1.44269504089f;

  const ushort* kB = kxF + (size_t)bh * (64 * 2048) + (size_t)w * 2048 + h * 256 + c * 8;
  const ushort* vB = vxF + (size_t)bh * (64 * 2048) + (size_t)w * 2048 + h * 256 + c * 8;
  for (int i = 0; i < 16; i++) {
    const ushort* kt = kB + (size_t)i * 4 * 2048;
    const ushort* vt = vB + (size_t)i * 4 * 2048;
    bf16x8 kf0 = *(const bf16x8*)(kt);
    bf16x8 kf1 = *(const bf16x8*)(kt + 512);
    bf16x8 kf2 = *(const bf16x8*)(kt + 1024);
    bf16x8 kf3 = *(const bf16x8*)(kt + 1536);
    bf16x8 vf00 = *(const bf16x8*)(vt);
    bf16x8 vf01 = *(const bf16x8*)(vt + 512);
    bf16x8 vf10 = *(const bf16x8*)(vt + 1024);
    bf16x8 vf11 = *(const bf16x8*)(vt + 1536);
    // S^T[key][q] : A = K rows=keys, B = Q cols=q
    f32x16 s;
#pragma unroll
    for (int j = 0; j < 16; j++) s[j] = 0.f;
    s = __builtin_amdgcn_mfma_f32_32x32x16_bf16(kf0, qf0, s, 0, 0, 0);
    s = __builtin_amdgcn_mfma_f32_32x32x16_bf16(kf1, qf1, s, 0, 0, 0);
    s = __builtin_amdgcn_mfma_f32_32x32x16_bf16(kf2, qf2, s, 0, 0, 0);
    s = __builtin_amdgcn_mfma_f32_32x32x16_bf16(kf3, qf3, s, 0, 0, 0);
    // lane-local online softmax (lane owns q = c; keys = (reg&3)+8*(reg>>2)+4h)
    float pmax = s[0];
#pragma unroll
    for (int j = 1; j < 16; j++) pmax = fmaxf(pmax, s[j]);
    pmax = fmaxf(pmax, __shfl_xor(pmax, 32, 64));
    float mn = fmaxf(m, pmax * cs);
    float resc = __builtin_amdgcn_exp2f(m - mn);
    m = mn;
    float psum = 0.f;
#pragma unroll
    for (int j = 0; j < 16; j++) {
      float pv = __builtin_amdgcn_exp2f(fmaf(s[j], cs, -mn));
      s[j] = pv;
      psum += pv;
    }
    psum += __shfl_xor(psum, 32, 64);
    lsum = fmaf(lsum, resc, psum);
#pragma unroll
    for (int j = 0; j < 16; j++) { accO0[j] *= resc; accO1[j] *= resc; }
    // pack P^T to bf16 dwords (pairs of regs) and cross-half exchange
    int pk0 = cvtpk(s[0],  s[1]);
    int pk1 = cvtpk(s[2],  s[3]);
    int pk2 = cvtpk(s[4],  s[5]);
    int pk3 = cvtpk(s[6],  s[7]);
    int pk4 = cvtpk(s[8],  s[9]);
    int pk5 = cvtpk(s[10], s[11]);
    int pk6 = cvtpk(s[12], s[13]);
    int pk7 = cvtpk(s[14], s[15]);
    int X00 = __shfl_xor(h ? pk0 : pk2, 32, 64);
    int X01 = __shfl_xor(h ? pk1 : pk3, 32, 64);
    int X10 = __shfl_xor(h ? pk4 : pk6, 32, 64);
    int X11 = __shfl_xor(h ? pk5 : pk7, 32, 64);
    union { int d[4]; bf16x8 v; } pf0, pf1;
    pf0.d[0] = h ? X00 : pk0;
    pf0.d[1] = h ? X01 : pk1;
    pf0.d[2] = h ? pk2 : X00;
    pf0.d[3] = h ? pk3 : X01;
    pf1.d[0] = h ? X10 : pk4;
    pf1.d[1] = h ? X11 : pk5;
    pf1.d[2] = h ? pk6 : X10;
    pf1.d[3] = h ? pk7 : X11;
    // O^T += V^T * P^T
    accO0 = __builtin_amdgcn_mfma_f32_32x32x16_bf16(vf00, pf0.v, accO0, 0, 0, 0);
    accO1 = __builtin_amdgcn_mfma_f32_32x32x16_bf16(vf01, pf0.v, accO1, 0, 0, 0);
    accO0 = __builtin_amdgcn_mfma_f32_32x32x16_bf16(vf10, pf1.v, accO0, 0, 0, 0);
    accO1 = __builtin_amdgcn_mfma_f32_32x32x16_bf16(vf11, pf1.v, accO1, 0, 0, 0);
  }
  // stash per-wave partials
#pragma unroll
  for (int reg = 0; reg < 16; reg++) {
    int d = (reg & 3) + 8 * (reg >> 2) + 4 * h;
    Wacc[w][c][d]      = accO0[reg];
    Wacc[w][c][32 + d] = accO1[reg];
  }
  if (h == 0) { Wm[w][c] = m; Wl[w][c] = lsum; }
  __syncthreads();
  // merge 4 key-partials + inverse pose + bf16 write
  int q = tid >> 3, oct = tid & 7;
  int b = bh >> 3, hh = bh & 7;
  int n = qb * 32 + q;
  float m0 = Wm[0][q], m1 = Wm[1][q], m2 = Wm[2][q], m3 = Wm[3][q];
  float ms = fmaxf(fmaxf(m0, m1), fmaxf(m2, m3));
  float e0 = __builtin_amdgcn_exp2f(m0 - ms);
  float e1 = __builtin_amdgcn_exp2f(m1 - ms);
  float e2 = __builtin_amdgcn_exp2f(m2 - ms);
  float e3 = __builtin_amdgcn_exp2f(m3 - ms);
  float lt = e0 * Wl[0][q] + e1 * Wl[1][q] + e2 * Wl[2][q] + e3 * Wl[3][q];
  float inv = 1.0f / lt;
  float od[8];
#pragma unroll
  for (int j = 0; j < 8; j++) {
    int d = oct * 8 + j;
    od[j] = (e0 * Wacc[0][q][d] + e1 * Wacc[1][q][d] +
             e2 * Wacc[2][q][d] + e3 * Wacc[3][q][d]) * inv;
  }
  const float* P = poses + ((size_t)b * 2048 + n) * 16;
  float R00 = P[0], R01 = P[1], R02 = P[2],  t0 = P[3];
  float R10 = P[4], R11 = P[5], R12 = P[6],  t1 = P[7];
  float R20 = P[8], R21 = P[9], R22 = P[10], t2 = P[11];
  float ti0 = -(R00 * t0 + R10 * t1 + R20 * t2);
  float ti1 = -(R01 * t0 + R11 * t1 + R21 * t2);
  float ti2 = -(R02 * t0 + R12 * t1 + R22 * t2);
  union { ushort u[8]; uint4 v; } ob;
#pragma unroll
  for (int g = 0; g < 2; g++) {
    float a0 = od[4 * g], a1 = od[4 * g + 1], a2 = od[4 * g + 2], a3 = od[4 * g + 3];
    ob.u[4 * g + 0] = f2b(R00 * a0 + R10 * a1 + R20 * a2 + ti0 * a3);
    ob.u[4 * g + 1] = f2b(R01 * a0 + R11 * a1 + R21 * a2 + ti1 * a3);
    ob.u[4 * g + 2] = f2b(R02 * a0 + R12 * a1 + R22 * a2 + ti2 * a3);
    ob.u[4 * g + 3] = f2b(a3);
  }
  *(uint4*)(obuf + ((size_t)b * 2048 + n) * 512 + hh * 64 + oct * 8) = ob.v;
}

extern "C" void kernel_launch(void* const* d_in, const int* in_sizes, int n_in,
                              void* d_out, int out_size, void* d_ws, size_t ws_size,
                              hipStream_t stream) {
  const float* x     = (const float*)d_in[0];
  const float* poses = (const float*)d_in[1];
  const float* w_qkv = (const float*)d_in[2];
  const float* b_qkv = (const float*)d_in[3];
  const float* w_out = (const float*)d_in[4];
  const float* b_out = (const float*)d_in[5];
  float* out = (float*)d_out;
  char* ws = (char*)d_ws;
  const size_t MB = 1024 * 1024;
  ushort* xb    = (ushort*)(ws);            // 4 MB
  ushort* wqkvT = (ushort*)(ws + 4 * MB);   // 1.5 MB
  ushort* woutT = (ushort*)(ws + 6 * MB);   // 0.5 MB
  float*  qkvf  = (float*)(ws + 8 * MB);    // 24 MB [4096][1536]
  ushort* obuf  = (ushort*)(ws + 8 * MB);   // 4 MB, reuses qkvf region (dead after kposef2)
  ushort* qxb   = (ushort*)(ws + 32 * MB);  // 4 MB
  ushort* kxFb  = (ushort*)(ws + 36 * MB);  // 4 MB
  ushort* vxFb  = (ushort*)(ws + 40 * MB);  // 4 MB

  kcastT<<<3072, 256, 0, stream>>>(w_qkv, wqkvT, 1536);
  kcastT<<<1024, 256, 0, stream>>>(w_out, woutT, 512);
  kcastx<<<2048, 256, 0, stream>>>(x, xb);
  dim3 g1(64, 24);
  kgemm<<<g1, 256, 0, stream>>>(xb, wqkvT, b_qkv, qkvf, 1536);
  kposef2<<<1024, 256, 0, stream>>>(qkvf, poses, qxb, kxFb, vxFb);
  kattn2<<<1024, 256, 0, stream>>>(qxb, kxFb, vxFb, poses, obuf);
  dim3 g2(64, 8);
  kgemm<<<g2, 256, 0, stream>>>(obuf, woutT, b_out, out, 512);
}

// Round 3
// 71.729 us; speedup vs baseline: 2.1604x; 1.3472x over previous
//
#include <hip/hip_runtime.h>

using f32x4  = __attribute__((ext_vector_type(4))) float;
using f32x16 = __attribute__((ext_vector_type(16))) float;
using bf16x8 = __attribute__((ext_vector_type(8))) short;

__device__ __forceinline__ ushort f2b(float x) {
  union { float f; unsigned u; } v; v.f = x;
  unsigned u = v.u;
  return (ushort)((u + 0x7FFFu + ((u >> 16) & 1u)) >> 16);
}

__device__ __forceinline__ int cvtpk(float lo, float hi) {
  int r;
  asm("v_cvt_pk_bf16_f32 %0, %1, %2" : "=v"(r) : "v"(lo), "v"(hi));
  return r;
}

__device__ __forceinline__ void gload16(const ushort* g, ushort* l) {
  __builtin_amdgcn_global_load_lds(
      (const __attribute__((address_space(1))) unsigned int*)g,
      (__attribute__((address_space(3))) unsigned int*)l, 16, 0, 0);
}

// ---- all casts in one launch ----
// blocks [0,3072): w_qkv -> wqkvT[n][k]; [3072,4096): w_out -> woutT; [4096,6144): x -> xb
__global__ __launch_bounds__(256) void kcastAll(const float* __restrict__ wqkv,
                                                const float* __restrict__ wout,
                                                const float* __restrict__ x,
                                                ushort* __restrict__ wqkvT,
                                                ushort* __restrict__ woutT,
                                                ushort* __restrict__ xb) {
  int blk = blockIdx.x;
  if (blk < 3072) {
    int i = blk * 256 + threadIdx.x;
    int n = i >> 9, k = i & 511;
    wqkvT[i] = f2b(wqkv[k * 1536 + n]);
  } else if (blk < 4096) {
    int i = (blk - 3072) * 256 + threadIdx.x;
    int n = i >> 9, k = i & 511;
    woutT[i] = f2b(wout[k * 512 + n]);
  } else {
    int t = (blk - 4096) * 256 + threadIdx.x;
    float4 v = ((const float4*)x)[t];
    ushort4 o;
    o.x = f2b(v.x); o.y = f2b(v.y); o.z = f2b(v.z); o.w = f2b(v.w);
    ((ushort4*)xb)[t] = o;
  }
}

// ---- fused GEMM1 (transposed output) + bias + forward pose maps ----
// Computes qkv^T[ch][tok]; lane's f32x4 = 4 consecutive channels of one token.
// Writes qx (row-major, pre-scaled by 0.125*log2e), kxF, vxF (MFMA-frag order).
__global__ __launch_bounds__(256) void kgemm1f(const ushort* __restrict__ W,   // wqkvT [1536][512]
                                               const ushort* __restrict__ X,   // xb    [4096][512]
                                               const float* __restrict__ bias, // b_qkv [1536]
                                               const float* __restrict__ poses,
                                               ushort* __restrict__ qx,
                                               ushort* __restrict__ kxF,
                                               ushort* __restrict__ vxF) {
  __shared__ __align__(16) ushort As[128 * 64];
  __shared__ __align__(16) ushort Bs[128 * 64];
  const int tid = threadIdx.x;
  const int w = tid >> 6, l = tid & 63;
  const int l15 = l & 15, lq = l >> 4;
  const int wr = w >> 1, wc = w & 1;
  const int bx = blockIdx.x, by = blockIdx.y;
  const ushort* Ag = W + (size_t)bx * 128 * 512;
  const ushort* Bg = X + (size_t)by * 128 * 512;
  const int srow = l >> 3, scol = (l & 7) * 8;
  f32x4 acc[4][4];
#pragma unroll
  for (int m = 0; m < 4; ++m)
#pragma unroll
    for (int n = 0; n < 4; ++n) acc[m][n] = (f32x4){0.f, 0.f, 0.f, 0.f};
  for (int kt = 0; kt < 8; ++kt) {
    __syncthreads();
    const int c0 = kt * 64 + scol;
#pragma unroll
    for (int i = 0; i < 4; ++i) {
      const int r = (w * 4 + i) * 8 + srow;
      gload16(Ag + (size_t)r * 512 + c0, &As[(w * 4 + i) * 512]);
      gload16(Bg + (size_t)r * 512 + c0, &Bs[(w * 4 + i) * 512]);
    }
    __syncthreads();
#pragma unroll
    for (int kk = 0; kk < 2; ++kk) {
      bf16x8 af[4], bfr[4];
#pragma unroll
      for (int m = 0; m < 4; ++m)
        af[m] = *(const bf16x8*)&As[(wr * 64 + m * 16 + l15) * 64 + kk * 32 + lq * 8];
#pragma unroll
      for (int n = 0; n < 4; ++n)
        bfr[n] = *(const bf16x8*)&Bs[(wc * 64 + n * 16 + l15) * 64 + kk * 32 + lq * 8];
#pragma unroll
      for (int m = 0; m < 4; ++m)
#pragma unroll
        for (int n = 0; n < 4; ++n)
          acc[m][n] = __builtin_amdgcn_mfma_f32_16x16x32_bf16(af[m], bfr[n], acc[m][n], 0, 0, 0);
    }
  }
  // ---- fused epilogue ----
  const int sec = bx >> 2;              // 0=q, 1=k, 2=v  (uniform per block)
  const int chBase = bx * 128 + wr * 64;
  const int tokBase = by * 128 + wc * 64;
  const float cs = 0.18033688011112042f;  // 0.125 * log2(e)
#pragma unroll
  for (int ns = 0; ns < 4; ++ns) {
    const int t = tokBase + ns * 16 + l15;
    const int b = t >> 11, n = t & 2047;
    float4 P0 = *(const float4*)(poses + (size_t)t * 16);
    float4 P1 = *(const float4*)(poses + (size_t)t * 16 + 4);
    float4 P2 = *(const float4*)(poses + (size_t)t * 16 + 8);
    const float ti0 = -(P0.x * P0.w + P1.x * P1.w + P2.x * P2.w);
    const float ti1 = -(P0.y * P0.w + P1.y * P1.w + P2.y * P2.w);
    const float ti2 = -(P0.z * P0.w + P1.z * P1.w + P2.z * P2.w);
    const int tile = n >> 5, cK = n & 31;
    const int kvsel = (n >> 4) & 1, hV = (n >> 3) & 1, jV = n & 7;
#pragma unroll
    for (int m = 0; m < 4; ++m) {
      const int ch = chBase + m * 16 + lq * 4;
      float4 bv = *(const float4*)(bias + ch);
      f32x4 a4 = acc[m][ns];
      const float a0 = a4[0] + bv.x, a1 = a4[1] + bv.y;
      const float a2 = a4[2] + bv.z, a3 = a4[3] + bv.w;
      const int cg = (ch - sec * 512) >> 2;
      const int hh = cg >> 4, cc = cg & 15;
      const int bh = b * 8 + hh;
      if (sec == 0) {
        ushort4 o;
        o.x = f2b(cs * (P0.x * a0 + P0.y * a1 + P0.z * a2));
        o.y = f2b(cs * (P1.x * a0 + P1.y * a1 + P1.z * a2));
        o.z = f2b(cs * (P2.x * a0 + P2.y * a1 + P2.z * a2));
        o.w = f2b(cs * (ti0 * a0 + ti1 * a1 + ti2 * a2 + a3));
        *(ushort4*)(qx + ((size_t)bh * 2048 + n) * 64 + cc * 4) = o;
      } else if (sec == 1) {
        ushort4 o;
        o.x = f2b(P0.x * a0 + P0.y * a1 + P0.z * a2 + P0.w * a3);
        o.y = f2b(P1.x * a0 + P1.y * a1 + P1.z * a2 + P1.w * a3);
        o.z = f2b(P2.x * a0 + P2.y * a1 + P2.z * a2 + P2.w * a3);
        o.w = f2b(a3);
        const int kkd = cc >> 2, hK = (cc >> 1) & 1, jK0 = (cc & 1) * 4;
        size_t kaddr = ((((size_t)bh * 64 + tile) * 4 + kkd) * 2 + hK) * 256 + cK * 8 + jK0;
        *(ushort4*)(kxF + kaddr) = o;
      } else {
        const ushort v0 = f2b(P0.x * a0 + P0.y * a1 + P0.z * a2 + P0.w * a3);
        const ushort v1 = f2b(P1.x * a0 + P1.y * a1 + P1.z * a2 + P1.w * a3);
        const ushort v2 = f2b(P2.x * a0 + P2.y * a1 + P2.z * a2 + P2.w * a3);
        const ushort v3 = f2b(a3);
        const int db = cc >> 3, cV0 = (cc * 4) & 31;
        size_t vaddr = (((((size_t)bh * 64 + tile) * 2 + kvsel) * 2 + db) * 2 + hV) * 256
                     + (size_t)cV0 * 8 + jV;
        vxF[vaddr]      = v0;
        vxF[vaddr + 8]  = v1;
        vxF[vaddr + 16] = v2;
        vxF[vaddr + 24] = v3;
      }
    }
  }
}

// ---- plain 128x128 GEMM (for the output projection), C = A * BT^T + bias ----
__global__ __launch_bounds__(256) void kgemm128(const ushort* __restrict__ A,
                                                const ushort* __restrict__ BT,
                                                const float* __restrict__ bias,
                                                float* __restrict__ C, int Nc) {
  __shared__ __align__(16) ushort As[128 * 64];
  __shared__ __align__(16) ushort Bs[128 * 64];
  const int tid = threadIdx.x;
  const int w = tid >> 6, l = tid & 63;
  const int l15 = l & 15, lq = l >> 4;
  const int wr = w >> 1, wc = w & 1;
  const int bx = blockIdx.x, by = blockIdx.y;
  const ushort* Ag = A + (size_t)bx * 128 * 512;
  const ushort* Bg = BT + (size_t)by * 128 * 512;
  const int srow = l >> 3, scol = (l & 7) * 8;
  f32x4 acc[4][4];
#pragma unroll
  for (int m = 0; m < 4; ++m)
#pragma unroll
    for (int n = 0; n < 4; ++n) acc[m][n] = (f32x4){0.f, 0.f, 0.f, 0.f};
  for (int kt = 0; kt < 8; ++kt) {
    __syncthreads();
    const int c0 = kt * 64 + scol;
#pragma unroll
    for (int i = 0; i < 4; ++i) {
      const int r = (w * 4 + i) * 8 + srow;
      gload16(Ag + (size_t)r * 512 + c0, &As[(w * 4 + i) * 512]);
      gload16(Bg + (size_t)r * 512 + c0, &Bs[(w * 4 + i) * 512]);
    }
    __syncthreads();
#pragma unroll
    for (int kk = 0; kk < 2; ++kk) {
      bf16x8 af[4], bfr[4];
#pragma unroll
      for (int m = 0; m < 4; ++m)
        af[m] = *(const bf16x8*)&As[(wr * 64 + m * 16 + l15) * 64 + kk * 32 + lq * 8];
#pragma unroll
      for (int n = 0; n < 4; ++n)
        bfr[n] = *(const bf16x8*)&Bs[(wc * 64 + n * 16 + l15) * 64 + kk * 32 + lq * 8];
#pragma unroll
      for (int m = 0; m < 4; ++m)
#pragma unroll
        for (int n = 0; n < 4; ++n)
          acc[m][n] = __builtin_amdgcn_mfma_f32_16x16x32_bf16(af[m], bfr[n], acc[m][n], 0, 0, 0);
    }
  }
#pragma unroll
  for (int ns = 0; ns < 4; ++ns) {
    const int col = by * 128 + wc * 64 + ns * 16 + l15;
    const float bvv = bias[col];
#pragma unroll
    for (int m = 0; m < 4; ++m) {
      const int row = bx * 128 + wr * 64 + m * 16 + lq * 4;
#pragma unroll
      for (int r = 0; r < 4; ++r)
        C[(size_t)(row + r) * Nc + col] = acc[m][ns][r] + bvv;
    }
  }
}

// ---- attention: WG=(bh, 64 q), 4 waves key-split, QB=64, defer-max, XCD-local K/V ----
__global__ __launch_bounds__(256, 2) void kattn3(const ushort* __restrict__ qx,
                                                 const ushort* __restrict__ kxF,
                                                 const ushort* __restrict__ vxF,
                                                 const float* __restrict__ poses,
                                                 ushort* __restrict__ obuf) {
  __shared__ float Wacc[4][32][68];
  __shared__ float Wm[4][32];
  __shared__ float Wl[4][32];
  const int tid = threadIdx.x;
  const int w = tid >> 6;
  const int l = tid & 63;
  const int c = l & 31;
  const int h = l >> 5;
  const int bid = blockIdx.x;
  const int xcd = bid & 7, idx = bid >> 3;
  const int bh = xcd * 2 + (idx >> 5);   // 2 bh per XCD -> K/V L2-resident
  const int qb = idx & 31;               // 64 q-rows per WG

  const ushort* qp = qx + ((size_t)bh * 2048 + qb * 64 + c) * 64 + h * 8;
  bf16x8 qfA[4], qfB[4];
#pragma unroll
  for (int j = 0; j < 4; ++j) {
    qfA[j] = *(const bf16x8*)(qp + j * 16);
    qfB[j] = *(const bf16x8*)(qp + 32 * 64 + j * 16);
  }
  f32x16 aA0, aA1, aB0, aB1;
#pragma unroll
  for (int j = 0; j < 16; ++j) { aA0[j] = 0.f; aA1[j] = 0.f; aB0[j] = 0.f; aB1[j] = 0.f; }
  float mA = -INFINITY, lA = 0.f, mB = -INFINITY, lB = 0.f;

  const ushort* kBp = kxF + (size_t)bh * (64 * 2048) + (size_t)w * 2048 + h * 256 + c * 8;
  const ushort* vBp = vxF + (size_t)bh * (64 * 2048) + (size_t)w * 2048 + h * 256 + c * 8;

  auto process = [&](f32x16& s, float& m, float& lsum, f32x16& a0, f32x16& a1,
                     const bf16x8& vf00, const bf16x8& vf01,
                     const bf16x8& vf10, const bf16x8& vf11) {
    float pmax = s[0];
#pragma unroll
    for (int j = 1; j < 16; ++j) pmax = fmaxf(pmax, s[j]);
    pmax = fmaxf(pmax, __shfl_xor(pmax, 32, 64));
    if (__any(pmax > m + 8.f)) {        // defer-max: rescale only when needed
      float mn = fmaxf(m, pmax);
      float rs = __builtin_amdgcn_exp2f(m - mn);
      m = mn;
      lsum *= rs;
#pragma unroll
      for (int j = 0; j < 16; ++j) { a0[j] *= rs; a1[j] *= rs; }
    }
    float psum = 0.f;
#pragma unroll
    for (int j = 0; j < 16; ++j) {
      float p = __builtin_amdgcn_exp2f(s[j] - m);
      s[j] = p;
      psum += p;
    }
    psum += __shfl_xor(psum, 32, 64);
    lsum += psum;
    int pk0 = cvtpk(s[0],  s[1]);
    int pk1 = cvtpk(s[2],  s[3]);
    int pk2 = cvtpk(s[4],  s[5]);
    int pk3 = cvtpk(s[6],  s[7]);
    int pk4 = cvtpk(s[8],  s[9]);
    int pk5 = cvtpk(s[10], s[11]);
    int pk6 = cvtpk(s[12], s[13]);
    int pk7 = cvtpk(s[14], s[15]);
    int X00 = __shfl_xor(h ? pk0 : pk2, 32, 64);
    int X01 = __shfl_xor(h ? pk1 : pk3, 32, 64);
    int X10 = __shfl_xor(h ? pk4 : pk6, 32, 64);
    int X11 = __shfl_xor(h ? pk5 : pk7, 32, 64);
    union { int d[4]; bf16x8 v; } pf0, pf1;
    pf0.d[0] = h ? X00 : pk0;
    pf0.d[1] = h ? X01 : pk1;
    pf0.d[2] = h ? pk2 : X00;
    pf0.d[3] = h ? pk3 : X01;
    pf1.d[0] = h ? X10 : pk4;
    pf1.d[1] = h ? X11 : pk5;
    pf1.d[2] = h ? pk6 : X10;
    pf1.d[3] = h ? pk7 : X11;
    a0 = __builtin_amdgcn_mfma_f32_32x32x16_bf16(vf00, pf0.v, a0, 0, 0, 0);
    a1 = __builtin_amdgcn_mfma_f32_32x32x16_bf16(vf01, pf0.v, a1, 0, 0, 0);
    a0 = __builtin_amdgcn_mfma_f32_32x32x16_bf16(vf10, pf1.v, a0, 0, 0, 0);
    a1 = __builtin_amdgcn_mfma_f32_32x32x16_bf16(vf11, pf1.v, a1, 0, 0, 0);
  };

  for (int i = 0; i < 16; ++i) {
    const ushort* kt = kBp + (size_t)i * 4 * 2048;
    const ushort* vt = vBp + (size_t)i * 4 * 2048;
    bf16x8 kf0 = *(const bf16x8*)(kt);
    bf16x8 kf1 = *(const bf16x8*)(kt + 512);
    bf16x8 kf2 = *(const bf16x8*)(kt + 1024);
    bf16x8 kf3 = *(const bf16x8*)(kt + 1536);
    bf16x8 vf00 = *(const bf16x8*)(vt);
    bf16x8 vf01 = *(const bf16x8*)(vt + 512);
    bf16x8 vf10 = *(const bf16x8*)(vt + 1024);
    bf16x8 vf11 = *(const bf16x8*)(vt + 1536);
    f32x16 s;
#pragma unroll
    for (int j = 0; j < 16; ++j) s[j] = 0.f;
    s = __builtin_amdgcn_mfma_f32_32x32x16_bf16(kf0, qfA[0], s, 0, 0, 0);
    s = __builtin_amdgcn_mfma_f32_32x32x16_bf16(kf1, qfA[1], s, 0, 0, 0);
    s = __builtin_amdgcn_mfma_f32_32x32x16_bf16(kf2, qfA[2], s, 0, 0, 0);
    s = __builtin_amdgcn_mfma_f32_32x32x16_bf16(kf3, qfA[3], s, 0, 0, 0);
    process(s, mA, lA, aA0, aA1, vf00, vf01, vf10, vf11);
    f32x16 s2;
#pragma unroll
    for (int j = 0; j < 16; ++j) s2[j] = 0.f;
    s2 = __builtin_amdgcn_mfma_f32_32x32x16_bf16(kf0, qfB[0], s2, 0, 0, 0);
    s2 = __builtin_amdgcn_mfma_f32_32x32x16_bf16(kf1, qfB[1], s2, 0, 0, 0);
    s2 = __builtin_amdgcn_mfma_f32_32x32x16_bf16(kf2, qfB[2], s2, 0, 0, 0);
    s2 = __builtin_amdgcn_mfma_f32_32x32x16_bf16(kf3, qfB[3], s2, 0, 0, 0);
    process(s2, mB, lB, aB0, aB1, vf00, vf01, vf10, vf11);
  }

  const int b = bh >> 3, hh = bh & 7;
#pragma unroll
  for (int S = 0; S < 2; ++S) {
    // write this set's partials
    const f32x16& p0 = S ? aB0 : aA0;
    const f32x16& p1 = S ? aB1 : aA1;
    const float pm = S ? mB : mA;
    const float pl = S ? lB : lA;
    if (S) __syncthreads();             // wait for previous merge reads
#pragma unroll
    for (int reg = 0; reg < 16; ++reg) {
      int d = (reg & 3) + 8 * (reg >> 2) + 4 * h;
      Wacc[w][c][d]      = p0[reg];
      Wacc[w][c][32 + d] = p1[reg];
    }
    if (h == 0) { Wm[w][c] = pm; Wl[w][c] = pl; }
    __syncthreads();
    // merge 4 key-partials + inverse pose + store
    const int q = tid >> 3, oct = tid & 7;
    const int n = qb * 64 + S * 32 + q;
    float m0 = Wm[0][q], m1 = Wm[1][q], m2 = Wm[2][q], m3 = Wm[3][q];
    float ms = fmaxf(fmaxf(m0, m1), fmaxf(m2, m3));
    float e0 = __builtin_amdgcn_exp2f(m0 - ms);
    float e1 = __builtin_amdgcn_exp2f(m1 - ms);
    float e2 = __builtin_amdgcn_exp2f(m2 - ms);
    float e3 = __builtin_amdgcn_exp2f(m3 - ms);
    float lt = e0 * Wl[0][q] + e1 * Wl[1][q] + e2 * Wl[2][q] + e3 * Wl[3][q];
    float inv = 1.0f / lt;
    float od[8];
#pragma unroll
    for (int j = 0; j < 8; ++j) {
      int d = oct * 8 + j;
      od[j] = (e0 * Wacc[0][q][d] + e1 * Wacc[1][q][d] +
               e2 * Wacc[2][q][d] + e3 * Wacc[3][q][d]) * inv;
    }
    const float* P = poses + ((size_t)b * 2048 + n) * 16;
    float R00 = P[0], R01 = P[1], R02 = P[2],  t0 = P[3];
    float R10 = P[4], R11 = P[5], R12 = P[6],  t1 = P[7];
    float R20 = P[8], R21 = P[9], R22 = P[10], t2 = P[11];
    float ti0 = -(R00 * t0 + R10 * t1 + R20 * t2);
    float ti1 = -(R01 * t0 + R11 * t1 + R21 * t2);
    float ti2 = -(R02 * t0 + R12 * t1 + R22 * t2);
    union { ushort u[8]; uint4 v; } ob;
#pragma unroll
    for (int g = 0; g < 2; ++g) {
      float a0 = od[4 * g], a1 = od[4 * g + 1], a2 = od[4 * g + 2], a3 = od[4 * g + 3];
      ob.u[4 * g + 0] = f2b(R00 * a0 + R10 * a1 + R20 * a2 + ti0 * a3);
      ob.u[4 * g + 1] = f2b(R01 * a0 + R11 * a1 + R21 * a2 + ti1 * a3);
      ob.u[4 * g + 2] = f2b(R02 * a0 + R12 * a1 + R22 * a2 + ti2 * a3);
      ob.u[4 * g + 3] = f2b(a3);
    }
    *(uint4*)(obuf + ((size_t)b * 2048 + n) * 512 + hh * 64 + oct * 8) = ob.v;
  }
}

extern "C" void kernel_launch(void* const* d_in, const int* in_sizes, int n_in,
                              void* d_out, int out_size, void* d_ws, size_t ws_size,
                              hipStream_t stream) {
  const float* x     = (const float*)d_in[0];
  const float* poses = (const float*)d_in[1];
  const float* w_qkv = (const float*)d_in[2];
  const float* b_qkv = (const float*)d_in[3];
  const float* w_out = (const float*)d_in[4];
  const float* b_out = (const float*)d_in[5];
  float* out = (float*)d_out;
  char* ws = (char*)d_ws;
  const size_t MB = 1024 * 1024;
  ushort* xb    = (ushort*)(ws);             // 4 MB
  ushort* wqkvT = (ushort*)(ws + 4 * MB);    // 1.5 MB
  ushort* woutT = (ushort*)(ws + 6 * MB);    // 0.5 MB
  ushort* qxb   = (ushort*)(ws + 8 * MB);    // 4 MB
  ushort* kxFb  = (ushort*)(ws + 12 * MB);   // 4 MB
  ushort* vxFb  = (ushort*)(ws + 16 * MB);   // 4 MB
  ushort* obuf  = (ushort*)(ws + 20 * MB);   // 4 MB

  kcastAll<<<6144, 256, 0, stream>>>(w_qkv, w_out, x, wqkvT, woutT, xb);
  dim3 g1(12, 32);
  kgemm1f<<<g1, 256, 0, stream>>>(wqkvT, xb, b_qkv, poses, qxb, kxFb, vxFb);
  kattn3<<<512, 256, 0, stream>>>(qxb, kxFb, vxFb, poses, obuf);
  dim3 g2(32, 4);
  kgemm128<<<g2, 256, 0, stream>>>(obuf, woutT, b_out, out, 512);
}